// Round 1
// baseline (134797.522 us; speedup 1.0000x reference)
//
#include <hip/hip_runtime.h>

// ---------------------------------------------------------------------------
// 2-layer LSTM LM forward, MI355X persistent-kernel design.
//
//   round r (1..4097):  layer0 computes step r, layer1 computes step r-1.
//   h vectors travel between blocks as bf16 pairs via device-scope atomics,
//   one release-flag per block per round; 256 blocks == 256 CUs, weights
//   resident in LDS as pre-swizzled MFMA B-fragments.
// ---------------------------------------------------------------------------

#define T_SEQ 4096
#define HID   1024
#define EMBD  512
#define VOCAB 50257
#define NBLK  256
#define TPB   512
#define UB    4      // hidden units per block per layer
#define NSEG0 48     // (EMBD+HID)/32 k-segments, layer 0
#define NSEG1 64     // (HID+HID)/32  k-segments, layer 1

// workspace layout (32-bit words)
#define WS_FLAGS 0                 // [256]
#define WS_H0R   256               // uint[2][512]  h0 ring, bf16 pairs
#define WS_H1R   1280              // uint[2][512]  h1 ring
#define WS_H1F   2304              // float[1024]   final h1 (f32)
#define WS_LOG   3328              // float[50257]  logits
#define WS_LSE   53600             // float[1]

// LDS layout (bytes)
#define OFF_W0 0                   // short8[NSEG0*64]  = 49152
#define OFF_W1 49152               // short8[NSEG1*64]  = 65536
#define OFF_V0 114688              // bf16[1536]  (x_t || h0_{r-1})
#define OFF_V1 117760              // bf16[2048]  (h0_{r-1} || h1_{r-2})
#define OFF_GP 121856              // float[4][16] gate partials
#define OFF_B0 122112              // float[16]
#define OFF_B1 122176              // float[16]
#define SMEM_BYTES 122240

typedef __attribute__((ext_vector_type(8))) short short8;
typedef __attribute__((ext_vector_type(4))) float f32x4;

__device__ __forceinline__ unsigned short f2bf(float f) {
  unsigned int u = __float_as_uint(f);
  u += 0x7FFFu + ((u >> 16) & 1u);          // round-to-nearest-even
  return (unsigned short)(u >> 16);
}
__device__ __forceinline__ unsigned int pack2bf(float a, float b) {
  return (unsigned int)f2bf(a) | ((unsigned int)f2bf(b) << 16);
}
__device__ __forceinline__ float sigmoidf_(float x) {
  return 1.f / (1.f + __expf(-x));
}

// one quarter of the round's matvec work: CNT MFMA k-segments.
// A-operand: v replicated into all 16 rows (any lane->k map cancels vs B).
// B-operand: 16 gate-rows as columns, pre-swizzled in LDS.
// D: col = lane&15 = gate-row (HW-verified layout); rows redundant.
template<int CNT>
__device__ __forceinline__ void mm_part(const short8* vf, const short8* wf,
                                        int s0, int lane, float* gout) {
  f32x4 a0 = {0.f, 0.f, 0.f, 0.f};
  f32x4 a1 = a0, a2 = a0, a3 = a0;
  const int grp = lane >> 4;
#pragma unroll
  for (int i = 0; i < CNT; ++i) {
    const int seg = s0 + i;
    short8 av = vf[seg * 4 + grp];      // broadcast across lanes 0-15
    short8 bv = wf[seg * 64 + lane];    // contiguous 1KB/wave, conflict-free
    if ((i & 3) == 0)      a0 = __builtin_amdgcn_mfma_f32_16x16x32_bf16(av, bv, a0, 0, 0, 0);
    else if ((i & 3) == 1) a1 = __builtin_amdgcn_mfma_f32_16x16x32_bf16(av, bv, a1, 0, 0, 0);
    else if ((i & 3) == 2) a2 = __builtin_amdgcn_mfma_f32_16x16x32_bf16(av, bv, a2, 0, 0, 0);
    else                   a3 = __builtin_amdgcn_mfma_f32_16x16x32_bf16(av, bv, a3, 0, 0, 0);
  }
  f32x4 s = (a0 + a1) + (a2 + a3);
  if (lane < 16) gout[lane] = s[0];
}

// ---------------------------------------------------------------------------
__global__ __launch_bounds__(TPB, 1) void reset_kernel(
    const float* __restrict__ h0in, unsigned int* __restrict__ ws) {
  const int tid = threadIdx.x;
  if (tid < NBLK) ws[WS_FLAGS + tid] = 0u;
  // ring slot 0 <- initial hidden states (bf16 pairs)
  ws[WS_H0R + tid] = pack2bf(h0in[2 * tid], h0in[2 * tid + 1]);
  ws[WS_H1R + tid] = pack2bf(h0in[HID + 2 * tid], h0in[HID + 2 * tid + 1]);
}

// ---------------------------------------------------------------------------
__global__ __launch_bounds__(TPB, 1) void scan_kernel(
    const int* __restrict__ tok,
    const float* __restrict__ h0in, const float* __restrict__ c0in,
    const float* __restrict__ emb,
    const float* __restrict__ wih0, const float* __restrict__ whh0,
    const float* __restrict__ bih0, const float* __restrict__ bhh0,
    const float* __restrict__ wih1, const float* __restrict__ whh1,
    const float* __restrict__ bih1, const float* __restrict__ bhh1,
    float* __restrict__ dout, unsigned int* __restrict__ ws) {
  extern __shared__ char smem[];
  short8* W0f = reinterpret_cast<short8*>(smem + OFF_W0);
  short8* W1f = reinterpret_cast<short8*>(smem + OFF_W1);
  unsigned int* v0w = reinterpret_cast<unsigned int*>(smem + OFF_V0);
  unsigned int* v1w = reinterpret_cast<unsigned int*>(smem + OFF_V1);
  const short8* v0f = reinterpret_cast<const short8*>(smem + OFF_V0);
  const short8* v1f = reinterpret_cast<const short8*>(smem + OFF_V1);
  float* gp  = reinterpret_cast<float*>(smem + OFF_GP);
  float* bs0 = reinterpret_cast<float*>(smem + OFF_B0);
  float* bs1 = reinterpret_cast<float*>(smem + OFF_B1);

  const int tid = threadIdx.x;
  const int bid = blockIdx.x;
  const int lane = tid & 63;
  const int w = tid >> 6;

  // ---- stage weights into LDS as pre-swizzled B-fragments (bf16) ----
  // block owns gate rows grow = q*HID + bid*UB + u  (q=gate i/f/g/o, u=unit)
  for (int slot = tid; slot < NSEG0 * 64; slot += TPB) {
    const int seg = slot >> 6, l = slot & 63;
    const int col = l & 15, grp = l >> 4;
    const int grow = (col >> 2) * HID + bid * UB + (col & 3);
    const int k0 = seg * 32 + grp * 8;
    const float* src = (k0 < EMBD) ? (wih0 + (size_t)grow * EMBD + k0)
                                   : (whh0 + (size_t)grow * HID + (k0 - EMBD));
    const float4* s4 = reinterpret_cast<const float4*>(src);
    float4 f0 = s4[0], f1 = s4[1];
    short8 pk;
    pk[0] = (short)f2bf(f0.x); pk[1] = (short)f2bf(f0.y);
    pk[2] = (short)f2bf(f0.z); pk[3] = (short)f2bf(f0.w);
    pk[4] = (short)f2bf(f1.x); pk[5] = (short)f2bf(f1.y);
    pk[6] = (short)f2bf(f1.z); pk[7] = (short)f2bf(f1.w);
    W0f[slot] = pk;
  }
  for (int slot = tid; slot < NSEG1 * 64; slot += TPB) {
    const int seg = slot >> 6, l = slot & 63;
    const int col = l & 15, grp = l >> 4;
    const int grow = (col >> 2) * HID + bid * UB + (col & 3);
    const int k0 = seg * 32 + grp * 8;
    const float* src = (k0 < HID) ? (wih1 + (size_t)grow * HID + k0)
                                  : (whh1 + (size_t)grow * HID + (k0 - HID));
    const float4* s4 = reinterpret_cast<const float4*>(src);
    float4 f0 = s4[0], f1 = s4[1];
    short8 pk;
    pk[0] = (short)f2bf(f0.x); pk[1] = (short)f2bf(f0.y);
    pk[2] = (short)f2bf(f0.z); pk[3] = (short)f2bf(f0.w);
    pk[4] = (short)f2bf(f1.x); pk[5] = (short)f2bf(f1.y);
    pk[6] = (short)f2bf(f1.z); pk[7] = (short)f2bf(f1.w);
    W1f[slot] = pk;
  }
  if (tid < 16) {
    const int grow = (tid >> 2) * HID + bid * UB + (tid & 3);
    bs0[tid] = bih0[grow] + bhh0[grow];
  } else if (tid < 32) {
    const int c = tid - 16;
    const int grow = (c >> 2) * HID + bid * UB + (c & 3);
    bs1[c] = bih1[grow] + bhh1[grow];
  }

  // cell state lives in tid0's registers (static indexing only)
  float c0r[UB], c1r[UB];
#pragma unroll
  for (int u = 0; u < UB; ++u) {
    c0r[u] = c0in[bid * UB + u];
    c1r[u] = c0in[HID + bid * UB + u];
  }

  // prefetch x for round 1
  float xa = 0.f, xb = 0.f;
  if (tid < 256) {
    const int t0 = tok[0];
    const float* xp = emb + (size_t)t0 * EMBD + tid * 2;
    xa = xp[0]; xb = xp[1];
  }

  unsigned int* flags = ws + WS_FLAGS;
  unsigned int* h0r = ws + WS_H0R;
  unsigned int* h1r = ws + WS_H1R;

  for (int r = 1; r <= T_SEQ + 1; ++r) {
    // ---- A: wait for all blocks to have published round r-1 ----
    if (tid < NBLK) {
      while ((int)__hip_atomic_load(&flags[tid], __ATOMIC_ACQUIRE,
                                    __HIP_MEMORY_SCOPE_AGENT) < r - 1) { }
    }
    __syncthreads();

    // ---- B: stage v0/v1 (bf16) into LDS ----
    {
      unsigned int d0 = __hip_atomic_load(&h0r[((r - 1) & 1) * 512 + tid],
                                          __ATOMIC_RELAXED, __HIP_MEMORY_SCOPE_AGENT);
      unsigned int d1 = __hip_atomic_load(&h1r[(r & 1) * 512 + tid],   // (r-2)&1 == r&1
                                          __ATOMIC_RELAXED, __HIP_MEMORY_SCOPE_AGENT);
      v0w[256 + tid] = d0;   // v0[512..1535] = h0_{r-1}
      v1w[tid] = d0;         // v1[0..1023]   = h0_{r-1}
      v1w[512 + tid] = d1;   // v1[1024..2047]= h1_{r-2}
      if (tid < 256) {
        v0w[tid] = pack2bf(xa, xb);   // v0[0..511] = x_r
        const int ridx = (r < T_SEQ) ? r : (T_SEQ - 1);
        const int tn = tok[ridx];     // prefetch x for round r+1
        const float* xp = emb + (size_t)tn * EMBD + tid * 2;
        xa = xp[0]; xb = xp[1];
      }
    }
    __syncthreads();

    // ---- C: MFMA matvec, waves 0-1 layer0, waves 2-3 layer1 ----
    if (w < 2) {
      if (r <= T_SEQ) mm_part<24>(v0f, W0f, w * 24, lane, gp + w * 16);
    } else if (w < 4) {
      if (r >= 2) mm_part<32>(v1f, W1f, (w - 2) * 32, lane, gp + w * 16);
    }
    __syncthreads();

    // ---- D: gate nonlinearities + state update + publish (tid0) ----
    if (tid == 0) {
      if (r <= T_SEQ) {
        float hv[UB];
#pragma unroll
        for (int u = 0; u < UB; ++u) {
          const float gi = gp[0 * 16 + 0 * 4 + u] + gp[1 * 16 + 0 * 4 + u] + bs0[0 * 4 + u];
          const float gf = gp[0 * 16 + 1 * 4 + u] + gp[1 * 16 + 1 * 4 + u] + bs0[1 * 4 + u];
          const float gg = gp[0 * 16 + 2 * 4 + u] + gp[1 * 16 + 2 * 4 + u] + bs0[2 * 4 + u];
          const float go = gp[0 * 16 + 3 * 4 + u] + gp[1 * 16 + 3 * 4 + u] + bs0[3 * 4 + u];
          const float c = sigmoidf_(gf) * c0r[u] + sigmoidf_(gi) * tanhf(gg);
          c0r[u] = c;
          hv[u] = sigmoidf_(go) * tanhf(c);
        }
        __hip_atomic_store(&h0r[(r & 1) * 512 + bid * 2 + 0], pack2bf(hv[0], hv[1]),
                           __ATOMIC_RELAXED, __HIP_MEMORY_SCOPE_AGENT);
        __hip_atomic_store(&h0r[(r & 1) * 512 + bid * 2 + 1], pack2bf(hv[2], hv[3]),
                           __ATOMIC_RELAXED, __HIP_MEMORY_SCOPE_AGENT);
        if (r == T_SEQ) {
#pragma unroll
          for (int u = 0; u < UB; ++u) {
            dout[VOCAB + bid * UB + u] = hv[u];               // h_n layer0
            dout[VOCAB + 2 * HID + bid * UB + u] = c0r[u];    // c_n layer0
          }
        }
      }
      if (r >= 2) {
        float hv[UB];
#pragma unroll
        for (int u = 0; u < UB; ++u) {
          const float gi = gp[2 * 16 + 0 * 4 + u] + gp[3 * 16 + 0 * 4 + u] + bs1[0 * 4 + u];
          const float gf = gp[2 * 16 + 1 * 4 + u] + gp[3 * 16 + 1 * 4 + u] + bs1[1 * 4 + u];
          const float gg = gp[2 * 16 + 2 * 4 + u] + gp[3 * 16 + 2 * 4 + u] + bs1[2 * 4 + u];
          const float go = gp[2 * 16 + 3 * 4 + u] + gp[3 * 16 + 3 * 4 + u] + bs1[3 * 4 + u];
          const float c = sigmoidf_(gf) * c1r[u] + sigmoidf_(gi) * tanhf(gg);
          c1r[u] = c;
          hv[u] = sigmoidf_(go) * tanhf(c);
        }
        __hip_atomic_store(&h1r[((r - 1) & 1) * 512 + bid * 2 + 0], pack2bf(hv[0], hv[1]),
                           __ATOMIC_RELAXED, __HIP_MEMORY_SCOPE_AGENT);
        __hip_atomic_store(&h1r[((r - 1) & 1) * 512 + bid * 2 + 1], pack2bf(hv[2], hv[3]),
                           __ATOMIC_RELAXED, __HIP_MEMORY_SCOPE_AGENT);
        if (r - 1 == T_SEQ) {
          float* h1f = reinterpret_cast<float*>(ws + WS_H1F);
#pragma unroll
          for (int u = 0; u < UB; ++u) {
            h1f[bid * UB + u] = hv[u];
            dout[VOCAB + HID + bid * UB + u] = hv[u];             // h_n layer1
            dout[VOCAB + 3 * HID + bid * UB + u] = c1r[u];        // c_n layer1
          }
        }
      }
      __hip_atomic_store(&flags[bid], (unsigned int)r,
                         __ATOMIC_RELEASE, __HIP_MEMORY_SCOPE_AGENT);
    }
    // no trailing barrier needed: next round's poll (incl. own flag) orders everything
  }
}

// ---------------------------------------------------------------------------
__global__ __launch_bounds__(256) void logits_kernel(
    const float* __restrict__ wout, const float* __restrict__ bout,
    unsigned int* __restrict__ ws) {
  const float* h1f = reinterpret_cast<const float*>(ws + WS_H1F);
  float* lg = reinterpret_cast<float*>(ws + WS_LOG);
  const int lane = threadIdx.x & 63;
  const int wv = threadIdx.x >> 6;
  const int gw = blockIdx.x * 4 + wv;    // 1024 waves total
  const float4* h4 = reinterpret_cast<const float4*>(h1f);
  float4 h[4];
#pragma unroll
  for (int j = 0; j < 4; ++j) h[j] = h4[j * 64 + lane];
  for (int v = gw; v < VOCAB; v += 1024) {
    const float4* wr = reinterpret_cast<const float4*>(wout + (size_t)v * HID);
    float s = 0.f;
#pragma unroll
    for (int j = 0; j < 4; ++j) {
      float4 x = wr[j * 64 + lane];
      s += x.x * h[j].x + x.y * h[j].y + x.z * h[j].z + x.w * h[j].w;
    }
#pragma unroll
    for (int m = 32; m >= 1; m >>= 1) s += __shfl_xor(s, m, 64);
    if (lane == 0) lg[v] = s + bout[v];
  }
}

__global__ __launch_bounds__(1024) void lse_kernel(unsigned int* __restrict__ ws) {
  const float* lg = reinterpret_cast<const float*>(ws + WS_LOG);
  __shared__ float wred[16];
  __shared__ float mshare;
  const int tid = threadIdx.x;
  float m = -3.4e38f;
  for (int i = tid; i < VOCAB; i += 1024) m = fmaxf(m, lg[i]);
#pragma unroll
  for (int s = 32; s >= 1; s >>= 1) m = fmaxf(m, __shfl_xor(m, s, 64));
  if ((tid & 63) == 0) wred[tid >> 6] = m;
  __syncthreads();
  if (tid == 0) {
    float mm = wred[0];
    for (int i = 1; i < 16; ++i) mm = fmaxf(mm, wred[i]);
    mshare = mm;
  }
  __syncthreads();
  const float M = mshare;
  float a = 0.f;
  for (int i = tid; i < VOCAB; i += 1024) a += __expf(lg[i] - M);
#pragma unroll
  for (int s = 32; s >= 1; s >>= 1) a += __shfl_xor(a, s, 64);
  __syncthreads();
  if ((tid & 63) == 0) wred[tid >> 6] = a;
  __syncthreads();
  if (tid == 0) {
    float ss = 0.f;
    for (int i = 0; i < 16; ++i) ss += wred[i];
    reinterpret_cast<float*>(ws + WS_LSE)[0] = M + logf(ss);
  }
}

__global__ __launch_bounds__(256) void out_kernel(
    const unsigned int* __restrict__ ws, float* __restrict__ dout) {
  const float lse = reinterpret_cast<const float*>(ws + WS_LSE)[0];
  const float* lg = reinterpret_cast<const float*>(ws + WS_LOG);
  const int i = blockIdx.x * 256 + threadIdx.x;
  if (i < VOCAB) dout[i] = lg[i] - lse;
}

// ---------------------------------------------------------------------------
extern "C" void kernel_launch(void* const* d_in, const int* in_sizes, int n_in,
                              void* d_out, int out_size, void* d_ws, size_t ws_size,
                              hipStream_t stream) {
  const int*   tok  = (const int*)d_in[0];
  const float* h0in = (const float*)d_in[1];
  const float* c0in = (const float*)d_in[2];
  const float* emb  = (const float*)d_in[3];
  const float* wih0 = (const float*)d_in[4];
  const float* whh0 = (const float*)d_in[5];
  const float* bih0 = (const float*)d_in[6];
  const float* bhh0 = (const float*)d_in[7];
  const float* wih1 = (const float*)d_in[8];
  const float* whh1 = (const float*)d_in[9];
  const float* bih1 = (const float*)d_in[10];
  const float* bhh1 = (const float*)d_in[11];
  const float* wout = (const float*)d_in[12];
  const float* bout = (const float*)d_in[13];
  float* out = (float*)d_out;
  unsigned int* ws = (unsigned int*)d_ws;

  (void)in_sizes; (void)n_in; (void)out_size; (void)ws_size;

  // allow >64KB dynamic LDS for the persistent kernel (idempotent, host-side)
  (void)hipFuncSetAttribute((const void*)scan_kernel,
                            hipFuncAttributeMaxDynamicSharedMemorySize, SMEM_BYTES);

  reset_kernel<<<1, TPB, 0, stream>>>(h0in, ws);
  scan_kernel<<<NBLK, TPB, SMEM_BYTES, stream>>>(
      tok, h0in, c0in, emb, wih0, whh0, bih0, bhh0,
      wih1, whh1, bih1, bhh1, out, ws);
  logits_kernel<<<256, 256, 0, stream>>>(wout, bout, ws);
  lse_kernel<<<1, 1024, 0, stream>>>(ws);
  out_kernel<<<(VOCAB + 255) / 256, 256, 0, stream>>>(ws, out);
}

// Round 2
// 34974.158 us; speedup vs baseline: 3.8542x; 3.8542x over previous
//
#include <hip/hip_runtime.h>

// ---------------------------------------------------------------------------
// 2-layer LSTM LM forward, MI355X persistent-kernel design.
//
//   round r (1..4097):  layer0 computes step r, layer1 computes step r-1.
//   h vectors travel between blocks as bf16 pairs; per-block flag with
//   RELAXED data-paired polling (thread tid polls the flag of the block
//   whose ring word it reads). 256 blocks == 256 CUs, weights resident in
//   LDS as pre-swizzled MFMA B-fragments.
// ---------------------------------------------------------------------------

#define T_SEQ 4096
#define HID   1024
#define EMBD  512
#define VOCAB 50257
#define NBLK  256
#define TPB   512
#define UB    4      // hidden units per block per layer
#define NSEG0 48     // (EMBD+HID)/32 k-segments, layer 0
#define NSEG1 64     // (HID+HID)/32  k-segments, layer 1

// workspace layout (32-bit words)
#define WS_FLAGS 0                 // [256]
#define WS_H0R   256               // uint[2][512]  h0 ring, bf16 pairs
#define WS_H1R   1280              // uint[2][512]  h1 ring
#define WS_H1F   2304              // float[1024]   final h1 (f32)
#define WS_LOG   3328              // float[50257]  logits
#define WS_LSE   53600             // float[1]

// LDS layout (bytes)
#define OFF_W0 0                   // short8[NSEG0*64]  = 49152
#define OFF_W1 49152               // short8[NSEG1*64]  = 65536
#define OFF_V0 114688              // bf16[1536]  (x_t || h0_{r-1})
#define OFF_V1 117760              // bf16[2048]  (h0_{r-1} || h1_{r-2})
#define OFF_GP 121856              // float[4][16] gate partials
#define OFF_B0 122112              // float[16]
#define OFF_B1 122176              // float[16]
#define SMEM_BYTES 122240

typedef __attribute__((ext_vector_type(8))) short short8;
typedef __attribute__((ext_vector_type(4))) float f32x4;

__device__ __forceinline__ unsigned short f2bf(float f) {
  unsigned int u = __float_as_uint(f);
  u += 0x7FFFu + ((u >> 16) & 1u);          // round-to-nearest-even
  return (unsigned short)(u >> 16);
}
__device__ __forceinline__ unsigned int pack2bf(float a, float b) {
  return (unsigned int)f2bf(a) | ((unsigned int)f2bf(b) << 16);
}
__device__ __forceinline__ float sigmoidf_(float x) {
  return 1.f / (1.f + __expf(-x));
}
__device__ __forceinline__ float tanhf_(float x) {
  // tanh(x) = 1 - 2/(e^{2x}+1); saturates correctly for large |x|
  return 1.f - 2.f / (__expf(2.f * x) + 1.f);
}

// one quarter of the round's matvec work: CNT MFMA k-segments.
// A-operand: v replicated into all 16 rows (any lane->k map cancels vs B).
// B-operand: 16 gate-rows as columns, pre-swizzled in LDS.
// D: col = lane&15 = gate-row (HW-verified layout); rows redundant.
template<int CNT>
__device__ __forceinline__ void mm_part(const short8* vf, const short8* wf,
                                        int s0, int lane, float* gout) {
  f32x4 a0 = {0.f, 0.f, 0.f, 0.f};
  f32x4 a1 = a0, a2 = a0, a3 = a0;
  const int grp = lane >> 4;
#pragma unroll
  for (int i = 0; i < CNT; ++i) {
    const int seg = s0 + i;
    short8 av = vf[seg * 4 + grp];      // broadcast across lanes 0-15
    short8 bv = wf[seg * 64 + lane];    // contiguous 1KB/wave, conflict-free
    if ((i & 3) == 0)      a0 = __builtin_amdgcn_mfma_f32_16x16x32_bf16(av, bv, a0, 0, 0, 0);
    else if ((i & 3) == 1) a1 = __builtin_amdgcn_mfma_f32_16x16x32_bf16(av, bv, a1, 0, 0, 0);
    else if ((i & 3) == 2) a2 = __builtin_amdgcn_mfma_f32_16x16x32_bf16(av, bv, a2, 0, 0, 0);
    else                   a3 = __builtin_amdgcn_mfma_f32_16x16x32_bf16(av, bv, a3, 0, 0, 0);
  }
  f32x4 s = (a0 + a1) + (a2 + a3);
  if (lane < 16) gout[lane] = s[0];
}

// ---------------------------------------------------------------------------
__global__ __launch_bounds__(TPB, 1) void reset_kernel(
    const float* __restrict__ h0in, unsigned int* __restrict__ ws) {
  const int tid = threadIdx.x;
  if (tid < NBLK) ws[WS_FLAGS + tid] = 0u;
  // ring slot 0 <- initial hidden states (bf16 pairs)
  ws[WS_H0R + tid] = pack2bf(h0in[2 * tid], h0in[2 * tid + 1]);
  ws[WS_H1R + tid] = pack2bf(h0in[HID + 2 * tid], h0in[HID + 2 * tid + 1]);
}

// ---------------------------------------------------------------------------
__global__ __launch_bounds__(TPB, 1) void scan_kernel(
    const int* __restrict__ tok,
    const float* __restrict__ h0in, const float* __restrict__ c0in,
    const float* __restrict__ emb,
    const float* __restrict__ wih0, const float* __restrict__ whh0,
    const float* __restrict__ bih0, const float* __restrict__ bhh0,
    const float* __restrict__ wih1, const float* __restrict__ whh1,
    const float* __restrict__ bih1, const float* __restrict__ bhh1,
    float* __restrict__ dout, unsigned int* __restrict__ ws) {
  extern __shared__ char smem[];
  short8* W0f = reinterpret_cast<short8*>(smem + OFF_W0);
  short8* W1f = reinterpret_cast<short8*>(smem + OFF_W1);
  unsigned int* v0w = reinterpret_cast<unsigned int*>(smem + OFF_V0);
  unsigned int* v1w = reinterpret_cast<unsigned int*>(smem + OFF_V1);
  const short8* v0f = reinterpret_cast<const short8*>(smem + OFF_V0);
  const short8* v1f = reinterpret_cast<const short8*>(smem + OFF_V1);
  float* gp  = reinterpret_cast<float*>(smem + OFF_GP);
  float* bs0 = reinterpret_cast<float*>(smem + OFF_B0);
  float* bs1 = reinterpret_cast<float*>(smem + OFF_B1);

  const int tid = threadIdx.x;
  const int bid = blockIdx.x;
  const int lane = tid & 63;
  const int w = tid >> 6;

  // ---- stage weights into LDS as pre-swizzled B-fragments (bf16) ----
  // block owns gate rows grow = q*HID + bid*UB + u  (q=gate i/f/g/o, u=unit)
  for (int slot = tid; slot < NSEG0 * 64; slot += TPB) {
    const int seg = slot >> 6, l = slot & 63;
    const int col = l & 15, grp = l >> 4;
    const int grow = (col >> 2) * HID + bid * UB + (col & 3);
    const int k0 = seg * 32 + grp * 8;
    const float* src = (k0 < EMBD) ? (wih0 + (size_t)grow * EMBD + k0)
                                   : (whh0 + (size_t)grow * HID + (k0 - EMBD));
    const float4* s4 = reinterpret_cast<const float4*>(src);
    float4 f0 = s4[0], f1 = s4[1];
    short8 pk;
    pk[0] = (short)f2bf(f0.x); pk[1] = (short)f2bf(f0.y);
    pk[2] = (short)f2bf(f0.z); pk[3] = (short)f2bf(f0.w);
    pk[4] = (short)f2bf(f1.x); pk[5] = (short)f2bf(f1.y);
    pk[6] = (short)f2bf(f1.z); pk[7] = (short)f2bf(f1.w);
    W0f[slot] = pk;
  }
  for (int slot = tid; slot < NSEG1 * 64; slot += TPB) {
    const int seg = slot >> 6, l = slot & 63;
    const int col = l & 15, grp = l >> 4;
    const int grow = (col >> 2) * HID + bid * UB + (col & 3);
    const int k0 = seg * 32 + grp * 8;
    const float* src = (k0 < HID) ? (wih1 + (size_t)grow * HID + k0)
                                  : (whh1 + (size_t)grow * HID + (k0 - HID));
    const float4* s4 = reinterpret_cast<const float4*>(src);
    float4 f0 = s4[0], f1 = s4[1];
    short8 pk;
    pk[0] = (short)f2bf(f0.x); pk[1] = (short)f2bf(f0.y);
    pk[2] = (short)f2bf(f0.z); pk[3] = (short)f2bf(f0.w);
    pk[4] = (short)f2bf(f1.x); pk[5] = (short)f2bf(f1.y);
    pk[6] = (short)f2bf(f1.z); pk[7] = (short)f2bf(f1.w);
    W1f[slot] = pk;
  }
  if (tid < 16) {
    const int grow = (tid >> 2) * HID + bid * UB + (tid & 3);
    bs0[tid] = bih0[grow] + bhh0[grow];
  } else if (tid < 32) {
    const int c = tid - 16;
    const int grow = (c >> 2) * HID + bid * UB + (c & 3);
    bs1[c] = bih1[grow] + bhh1[grow];
  }

  // cell state: lane u of wave 0 holds layer0 unit u; lane 4+u holds layer1
  float cst = 0.f;
  if (w == 0 && lane < 8) {
    const int u = lane & 3;
    cst = (lane < 4) ? c0in[bid * UB + u] : c0in[HID + bid * UB + u];
  }

  // prefetch x for round 1
  float xa = 0.f, xb = 0.f;
  if (tid < 256) {
    const int t0 = tok[0];
    const float* xp = emb + (size_t)t0 * EMBD + tid * 2;
    xa = xp[0]; xb = xp[1];
  }

  unsigned int* flags = ws + WS_FLAGS;
  unsigned int* h0r = ws + WS_H0R;
  unsigned int* h1r = ws + WS_H1R;

  for (int r = 1; r <= T_SEQ + 1; ++r) {
    // ---- A+B: data-paired poll, then immediately read this lane's ring words.
    // Thread tid reads ring word tid, produced by block tid>>1 -> poll that
    // flag only, RELAXED (no cache invalidates). Publisher's RELEASE flag
    // store ordered its h stores at the coherence point; our ring loads
    // bypass caches, and the loop's control dependency orders issue.
    {
      const int fidx = tid >> 1;
      while ((int)__hip_atomic_load(&flags[fidx], __ATOMIC_RELAXED,
                                    __HIP_MEMORY_SCOPE_AGENT) < r - 1) { }
      asm volatile("" ::: "memory");   // compiler barrier: no hoisting
      unsigned int d0 = __hip_atomic_load(&h0r[((r - 1) & 1) * 512 + tid],
                                          __ATOMIC_RELAXED, __HIP_MEMORY_SCOPE_AGENT);
      unsigned int d1 = __hip_atomic_load(&h1r[(r & 1) * 512 + tid],   // (r-2)&1 == r&1
                                          __ATOMIC_RELAXED, __HIP_MEMORY_SCOPE_AGENT);
      v0w[256 + tid] = d0;   // v0[512..1535] = h0_{r-1}
      v1w[tid] = d0;         // v1[0..1023]   = h0_{r-1}
      v1w[512 + tid] = d1;   // v1[1024..2047]= h1_{r-2}
      if (tid < 256) {
        v0w[tid] = pack2bf(xa, xb);   // v0[0..511] = x_r
        const int ridx = (r < T_SEQ) ? r : (T_SEQ - 1);
        const int tn = tok[ridx];     // prefetch x for round r+1
        const float* xp = emb + (size_t)tn * EMBD + tid * 2;
        xa = xp[0]; xb = xp[1];
      }
    }
    __syncthreads();

    // ---- C: MFMA matvec, waves 0-1 layer0, waves 2-3 layer1 ----
    if (w < 2) {
      if (r <= T_SEQ) mm_part<24>(v0f, W0f, w * 24, lane, gp + w * 16);
    } else if (w < 4) {
      if (r >= 2) mm_part<32>(v1f, W1f, (w - 2) * 32, lane, gp + w * 16);
    }
    __syncthreads();

    // ---- D: gates in parallel on wave-0 lanes 0-7 (lane = layer*4 + unit) ----
    if (w == 0) {
      float hv = 0.f;
      const int u = lane & 3;
      const bool isl1 = (lane & 4) != 0;
      if (lane < 8) {
        const bool act = isl1 ? (r >= 2) : (r <= T_SEQ);
        if (act) {
          const float* base = gp + (isl1 ? 32 : 0);
          const float* bsp  = isl1 ? bs1 : bs0;
          const float gi = base[u]      + base[16 + u]      + bsp[u];
          const float gf = base[4 + u]  + base[20 + u]      + bsp[4 + u];
          const float gg = base[8 + u]  + base[24 + u]      + bsp[8 + u];
          const float go = base[12 + u] + base[28 + u]      + bsp[12 + u];
          const float c = sigmoidf_(gf) * cst + sigmoidf_(gi) * tanhf_(gg);
          cst = c;
          hv = sigmoidf_(go) * tanhf_(c);
          if (!isl1 && r == T_SEQ) {
            dout[VOCAB + bid * UB + u] = hv;                // h_n layer0
            dout[VOCAB + 2 * HID + bid * UB + u] = cst;     // c_n layer0
          }
          if (isl1 && (r - 1) == T_SEQ) {
            float* h1f = reinterpret_cast<float*>(ws + WS_H1F);
            h1f[bid * UB + u] = hv;
            dout[VOCAB + HID + bid * UB + u] = hv;          // h_n layer1
            dout[VOCAB + 3 * HID + bid * UB + u] = cst;     // c_n layer1
          }
        }
      }
      // pack pairs via shfl and publish (lanes 0,1 -> h0; lanes 4,5 -> h1)
      const int ia = 2 * (lane & 1);
      const float a0 = __shfl(hv, ia),     b0 = __shfl(hv, ia + 1);
      const float a1 = __shfl(hv, 4 + ia), b1 = __shfl(hv, 5 + ia);
      if (lane < 2 && r <= T_SEQ) {
        __hip_atomic_store(&h0r[(r & 1) * 512 + bid * 2 + lane], pack2bf(a0, b0),
                           __ATOMIC_RELAXED, __HIP_MEMORY_SCOPE_AGENT);
      }
      if (lane >= 4 && lane < 6 && r >= 2) {
        __hip_atomic_store(&h1r[((r - 1) & 1) * 512 + bid * 2 + (lane - 4)], pack2bf(a1, b1),
                           __ATOMIC_RELAXED, __HIP_MEMORY_SCOPE_AGENT);
      }
      // release: h stores complete at coherence point before flag update
      if (lane == 0) {
        __hip_atomic_store(&flags[bid], (unsigned int)r,
                           __ATOMIC_RELEASE, __HIP_MEMORY_SCOPE_AGENT);
      }
    }
    // no trailing barrier: next round's data-paired polls gate every consumer
  }
}

// ---------------------------------------------------------------------------
__global__ __launch_bounds__(256) void logits_kernel(
    const float* __restrict__ wout, const float* __restrict__ bout,
    unsigned int* __restrict__ ws) {
  const float* h1f = reinterpret_cast<const float*>(ws + WS_H1F);
  float* lg = reinterpret_cast<float*>(ws + WS_LOG);
  const int lane = threadIdx.x & 63;
  const int wv = threadIdx.x >> 6;
  const int gw = blockIdx.x * 4 + wv;    // 1024 waves total
  const float4* h4 = reinterpret_cast<const float4*>(h1f);
  float4 h[4];
#pragma unroll
  for (int j = 0; j < 4; ++j) h[j] = h4[j * 64 + lane];
  for (int v = gw; v < VOCAB; v += 1024) {
    const float4* wr = reinterpret_cast<const float4*>(wout + (size_t)v * HID);
    float s = 0.f;
#pragma unroll
    for (int j = 0; j < 4; ++j) {
      float4 x = wr[j * 64 + lane];
      s += x.x * h[j].x + x.y * h[j].y + x.z * h[j].z + x.w * h[j].w;
    }
#pragma unroll
    for (int m = 32; m >= 1; m >>= 1) s += __shfl_xor(s, m, 64);
    if (lane == 0) lg[v] = s + bout[v];
  }
}

__global__ __launch_bounds__(1024) void lse_kernel(unsigned int* __restrict__ ws) {
  const float* lg = reinterpret_cast<const float*>(ws + WS_LOG);
  __shared__ float wred[16];
  __shared__ float mshare;
  const int tid = threadIdx.x;
  float m = -3.4e38f;
  for (int i = tid; i < VOCAB; i += 1024) m = fmaxf(m, lg[i]);
#pragma unroll
  for (int s = 32; s >= 1; s >>= 1) m = fmaxf(m, __shfl_xor(m, s, 64));
  if ((tid & 63) == 0) wred[tid >> 6] = m;
  __syncthreads();
  if (tid == 0) {
    float mm = wred[0];
    for (int i = 1; i < 16; ++i) mm = fmaxf(mm, wred[i]);
    mshare = mm;
  }
  __syncthreads();
  const float M = mshare;
  float a = 0.f;
  for (int i = tid; i < VOCAB; i += 1024) a += __expf(lg[i] - M);
#pragma unroll
  for (int s = 32; s >= 1; s >>= 1) a += __shfl_xor(a, s, 64);
  __syncthreads();
  if ((tid & 63) == 0) wred[tid >> 6] = a;
  __syncthreads();
  if (tid == 0) {
    float ss = 0.f;
    for (int i = 0; i < 16; ++i) ss += wred[i];
    reinterpret_cast<float*>(ws + WS_LSE)[0] = M + logf(ss);
  }
}

__global__ __launch_bounds__(256) void out_kernel(
    const unsigned int* __restrict__ ws, float* __restrict__ dout) {
  const float lse = reinterpret_cast<const float*>(ws + WS_LSE)[0];
  const float* lg = reinterpret_cast<const float*>(ws + WS_LOG);
  const int i = blockIdx.x * 256 + threadIdx.x;
  if (i < VOCAB) dout[i] = lg[i] - lse;
}

// ---------------------------------------------------------------------------
extern "C" void kernel_launch(void* const* d_in, const int* in_sizes, int n_in,
                              void* d_out, int out_size, void* d_ws, size_t ws_size,
                              hipStream_t stream) {
  const int*   tok  = (const int*)d_in[0];
  const float* h0in = (const float*)d_in[1];
  const float* c0in = (const float*)d_in[2];
  const float* emb  = (const float*)d_in[3];
  const float* wih0 = (const float*)d_in[4];
  const float* whh0 = (const float*)d_in[5];
  const float* bih0 = (const float*)d_in[6];
  const float* bhh0 = (const float*)d_in[7];
  const float* wih1 = (const float*)d_in[8];
  const float* whh1 = (const float*)d_in[9];
  const float* bih1 = (const float*)d_in[10];
  const float* bhh1 = (const float*)d_in[11];
  const float* wout = (const float*)d_in[12];
  const float* bout = (const float*)d_in[13];
  float* out = (float*)d_out;
  unsigned int* ws = (unsigned int*)d_ws;

  (void)in_sizes; (void)n_in; (void)out_size; (void)ws_size;

  (void)hipFuncSetAttribute((const void*)scan_kernel,
                            hipFuncAttributeMaxDynamicSharedMemorySize, SMEM_BYTES);

  reset_kernel<<<1, TPB, 0, stream>>>(h0in, ws);
  scan_kernel<<<NBLK, TPB, SMEM_BYTES, stream>>>(
      tok, h0in, c0in, emb, wih0, whh0, bih0, bhh0,
      wih1, whh1, bih1, bhh1, out, ws);
  logits_kernel<<<256, 256, 0, stream>>>(wout, bout, ws);
  lse_kernel<<<1, 1024, 0, stream>>>(ws);
  out_kernel<<<(VOCAB + 255) / 256, 256, 0, stream>>>(ws, out);
}

// Round 3
// 12721.518 us; speedup vs baseline: 10.5960x; 2.7492x over previous
//
#include <hip/hip_runtime.h>

// ---------------------------------------------------------------------------
// 2-layer LSTM LM forward, MI355X persistent-kernel design, round 3.
//
//   round r (1..4097): layer0 computes step r, layer1 computes step r-1.
//   h travels as TAG-EMBEDDED u64 words ((round<<32)|bf16x2), all RELAXED
//   agent atomics -> zero fences in the steady-state loop, single global
//   hop per round. 2-deep parity ring; correctness from the happens-before
//   chain: consumer reads r-1 before publishing r, producer polls r before
//   overwriting with r+1.
// ---------------------------------------------------------------------------

#define T_SEQ 4096
#define HID   1024
#define EMBD  512
#define VOCAB 50257
#define NBLK  256
#define TPB   512
#define UB    4      // hidden units per block per layer
#define NSEG0 48     // (EMBD+HID)/32 k-segments, layer 0
#define NSEG1 64     // (HID+HID)/32  k-segments, layer 1

// workspace layout (32-bit word offsets)
#define WS_H0T 0       // u64[2][512]: (tag<<32)|bf16pair  (2048 u32 words)
#define WS_H1T 2048    // u64[2][512]
#define WS_H1F 4096    // float[1024] final h1
#define WS_LOG 5120    // float[50257] logits
#define WS_LSE 55377   // float[1]

// LDS layout (bytes)
#define OFF_W0 0                   // short8[NSEG0*64]  = 49152
#define OFF_W1 49152               // short8[NSEG1*64]  = 65536
#define OFF_V0 114688              // bf16[1536]  (x_t || h0_{r-1})
#define OFF_V1 117760              // bf16[2048]  (h0_{r-1} || h1_{r-2})
#define OFF_GP 121856              // float[7][16] gate partials
#define OFF_B0 122304              // float[16]
#define OFF_B1 122368              // float[16]
#define SMEM_BYTES 122432

typedef __attribute__((ext_vector_type(8))) short short8;
typedef __attribute__((ext_vector_type(4))) float f32x4;
typedef unsigned long long u64;

__device__ __forceinline__ unsigned short f2bf(float f) {
  unsigned int u = __float_as_uint(f);
  u += 0x7FFFu + ((u >> 16) & 1u);          // round-to-nearest-even
  return (unsigned short)(u >> 16);
}
__device__ __forceinline__ unsigned int pack2bf(float a, float b) {
  return (unsigned int)f2bf(a) | ((unsigned int)f2bf(b) << 16);
}
__device__ __forceinline__ float sigmoidf_(float x) {
  return 1.f / (1.f + __expf(-x));
}
__device__ __forceinline__ float tanhf_(float x) {
  return 1.f - 2.f / (__expf(2.f * x) + 1.f);
}

// 16 MFMA k-segments of the matvec. A = v replicated (any lane->k map
// cancels vs B); B = 16 gate-rows as columns, pre-swizzled in LDS.
// D: col = lane&15 = gate-row (HW-verified C/D layout).
template<int CNT>
__device__ __forceinline__ void mm_part(const short8* vf, const short8* wf,
                                        int s0, int lane, float* gout) {
  f32x4 a0 = {0.f, 0.f, 0.f, 0.f};
  f32x4 a1 = a0, a2 = a0, a3 = a0;
  const int grp = lane >> 4;
#pragma unroll
  for (int i = 0; i < CNT; ++i) {
    const int seg = s0 + i;
    short8 av = vf[seg * 4 + grp];
    short8 bv = wf[seg * 64 + lane];
    if ((i & 3) == 0)      a0 = __builtin_amdgcn_mfma_f32_16x16x32_bf16(av, bv, a0, 0, 0, 0);
    else if ((i & 3) == 1) a1 = __builtin_amdgcn_mfma_f32_16x16x32_bf16(av, bv, a1, 0, 0, 0);
    else if ((i & 3) == 2) a2 = __builtin_amdgcn_mfma_f32_16x16x32_bf16(av, bv, a2, 0, 0, 0);
    else                   a3 = __builtin_amdgcn_mfma_f32_16x16x32_bf16(av, bv, a3, 0, 0, 0);
  }
  f32x4 s = (a0 + a1) + (a2 + a3);
  if (lane < 16) gout[lane] = s[0];
}

// ---------------------------------------------------------------------------
__global__ __launch_bounds__(TPB, 1) void reset_kernel(
    const float* __restrict__ h0in, unsigned int* __restrict__ ws) {
  const int tid = threadIdx.x;
  u64* H0T = reinterpret_cast<u64*>(ws + WS_H0T);
  u64* H1T = reinterpret_cast<u64*>(ws + WS_H1T);
  // slot 0 <- initial hidden states, tag 0 (only tag-0 slots are ever
  // expected before the first publish; see scan_kernel poll targets)
  H0T[tid] = (u64)pack2bf(h0in[2 * tid], h0in[2 * tid + 1]);
  H1T[tid] = (u64)pack2bf(h0in[HID + 2 * tid], h0in[HID + 2 * tid + 1]);
}

// ---------------------------------------------------------------------------
__global__ __launch_bounds__(TPB, 1) void scan_kernel(
    const int* __restrict__ tok,
    const float* __restrict__ h0in, const float* __restrict__ c0in,
    const float* __restrict__ emb,
    const float* __restrict__ wih0, const float* __restrict__ whh0,
    const float* __restrict__ bih0, const float* __restrict__ bhh0,
    const float* __restrict__ wih1, const float* __restrict__ whh1,
    const float* __restrict__ bih1, const float* __restrict__ bhh1,
    float* __restrict__ dout, unsigned int* __restrict__ ws) {
  extern __shared__ char smem[];
  short8* W0f = reinterpret_cast<short8*>(smem + OFF_W0);
  short8* W1f = reinterpret_cast<short8*>(smem + OFF_W1);
  unsigned int* v0w = reinterpret_cast<unsigned int*>(smem + OFF_V0);
  unsigned int* v1w = reinterpret_cast<unsigned int*>(smem + OFF_V1);
  const short8* v0f = reinterpret_cast<const short8*>(smem + OFF_V0);
  const short8* v1f = reinterpret_cast<const short8*>(smem + OFF_V1);
  float* gp  = reinterpret_cast<float*>(smem + OFF_GP);
  float* bs0 = reinterpret_cast<float*>(smem + OFF_B0);
  float* bs1 = reinterpret_cast<float*>(smem + OFF_B1);

  const int tid = threadIdx.x;
  const int bid = blockIdx.x;
  const int lane = tid & 63;
  const int w = tid >> 6;

  // ---- stage weights into LDS as pre-swizzled B-fragments (bf16) ----
  for (int slot = tid; slot < NSEG0 * 64; slot += TPB) {
    const int seg = slot >> 6, l = slot & 63;
    const int col = l & 15, grp = l >> 4;
    const int grow = (col >> 2) * HID + bid * UB + (col & 3);
    const int k0 = seg * 32 + grp * 8;
    const float* src = (k0 < EMBD) ? (wih0 + (size_t)grow * EMBD + k0)
                                   : (whh0 + (size_t)grow * HID + (k0 - EMBD));
    const float4* s4 = reinterpret_cast<const float4*>(src);
    float4 f0 = s4[0], f1 = s4[1];
    short8 pk;
    pk[0] = (short)f2bf(f0.x); pk[1] = (short)f2bf(f0.y);
    pk[2] = (short)f2bf(f0.z); pk[3] = (short)f2bf(f0.w);
    pk[4] = (short)f2bf(f1.x); pk[5] = (short)f2bf(f1.y);
    pk[6] = (short)f2bf(f1.z); pk[7] = (short)f2bf(f1.w);
    W0f[slot] = pk;
  }
  for (int slot = tid; slot < NSEG1 * 64; slot += TPB) {
    const int seg = slot >> 6, l = slot & 63;
    const int col = l & 15, grp = l >> 4;
    const int grow = (col >> 2) * HID + bid * UB + (col & 3);
    const int k0 = seg * 32 + grp * 8;
    const float* src = (k0 < HID) ? (wih1 + (size_t)grow * HID + k0)
                                  : (whh1 + (size_t)grow * HID + (k0 - HID));
    const float4* s4 = reinterpret_cast<const float4*>(src);
    float4 f0 = s4[0], f1 = s4[1];
    short8 pk;
    pk[0] = (short)f2bf(f0.x); pk[1] = (short)f2bf(f0.y);
    pk[2] = (short)f2bf(f0.z); pk[3] = (short)f2bf(f0.w);
    pk[4] = (short)f2bf(f1.x); pk[5] = (short)f2bf(f1.y);
    pk[6] = (short)f2bf(f1.z); pk[7] = (short)f2bf(f1.w);
    W1f[slot] = pk;
  }
  if (tid < 16) {
    const int grow = (tid >> 2) * HID + bid * UB + (tid & 3);
    bs0[tid] = bih0[grow] + bhh0[grow];
  } else if (tid < 32) {
    const int c = tid - 16;
    const int grow = (c >> 2) * HID + bid * UB + (c & 3);
    bs1[c] = bih1[grow] + bhh1[grow];
  }

  // cell state: wave0 lanes 0-3 hold layer0 c; wave3 lanes 0-3 hold layer1 c
  float cst = 0.f;
  if (w == 0 && lane < UB) cst = c0in[bid * UB + lane];
  if (w == 3 && lane < UB) cst = c0in[HID + bid * UB + lane];

  // prefetch x for round 1
  float xa = 0.f, xb = 0.f;
  if (tid < 256) {
    const float* xp = emb + (size_t)tok[0] * EMBD + tid * 2;
    xa = xp[0]; xb = xp[1];
  }

  u64* H0T = reinterpret_cast<u64*>(ws + WS_H0T);
  u64* H1T = reinterpret_cast<u64*>(ws + WS_H1T);

  for (int r = 1; r <= T_SEQ + 1; ++r) {
    // ---- write x_r to LDS from regs; issue x_{r+1} prefetch (drains during poll)
    if (tid < 256) {
      v0w[tid] = pack2bf(xa, xb);
      const int ridx = (r < T_SEQ) ? r : (T_SEQ - 1);
      const float* xp = emb + (size_t)tok[ridx] * EMBD + tid * 2;
      xa = xp[0]; xb = xp[1];
    }

    // ---- poll tag-embedded ring words (this thread's h0 word + h1 word) ----
    {
      const int p0 = (r - 1) & 1;          // h0_{r-1} lives in slot (r-1)&1
      const int p1 = r & 1;                // h1_{r-2} lives in slot (r-2)&1 == r&1
      const unsigned int tg0 = (unsigned int)(r - 1);
      const unsigned int tg1 = (unsigned int)(r - 2);
      const bool need1 = (r >= 2);
      u64 w0 = 0, w1 = 0;
      bool ok0 = false, ok1 = !need1;
      do {
        if (!ok0) {
          w0 = __hip_atomic_load(&H0T[p0 * 512 + tid], __ATOMIC_RELAXED,
                                 __HIP_MEMORY_SCOPE_AGENT);
          ok0 = ((unsigned int)(w0 >> 32) == tg0);
        }
        if (!ok1) {
          w1 = __hip_atomic_load(&H1T[p1 * 512 + tid], __ATOMIC_RELAXED,
                                 __HIP_MEMORY_SCOPE_AGENT);
          ok1 = ((unsigned int)(w1 >> 32) == tg1);
        }
      } while (!(ok0 && ok1));
      const unsigned int d0 = (unsigned int)w0;
      v0w[256 + tid] = d0;                 // v0[512..1535] = h0_{r-1}
      v1w[tid] = d0;                       // v1[0..1023]   = h0_{r-1}
      if (need1) v1w[512 + tid] = (unsigned int)w1;  // v1[1024..2047] = h1_{r-2}
    }
    __syncthreads();

    // ---- mm: waves 0-2 layer0 (48 segs), waves 3-6 layer1 (64 segs) ----
    if (w < 3) {
      if (r <= T_SEQ) mm_part<16>(v0f, W0f, w * 16, lane, gp + w * 16);
    } else if (w < 7) {
      if (r >= 2) mm_part<16>(v1f, W1f, (w - 3) * 16, lane, gp + w * 16);
    }
    __syncthreads();

    // ---- gates + tagged publish (wave0: layer0; wave3: layer1), no fence ----
    if (w == 0 && r <= T_SEQ) {
      float hv = 0.f;
      if (lane < UB) {
        const int u = lane;
        float gi = bs0[u], gf = bs0[4 + u], gg = bs0[8 + u], go = bs0[12 + u];
#pragma unroll
        for (int p = 0; p < 3; ++p) {
          gi += gp[p * 16 + u];      gf += gp[p * 16 + 4 + u];
          gg += gp[p * 16 + 8 + u];  go += gp[p * 16 + 12 + u];
        }
        const float c = sigmoidf_(gf) * cst + sigmoidf_(gi) * tanhf_(gg);
        cst = c;
        hv = sigmoidf_(go) * tanhf_(c);
        if (r == T_SEQ) {
          dout[VOCAB + bid * UB + u] = hv;              // h_n layer0
          dout[VOCAB + 2 * HID + bid * UB + u] = cst;   // c_n layer0
        }
      }
      const float a = __shfl(hv, 2 * (lane & 1));
      const float b = __shfl(hv, 2 * (lane & 1) + 1);
      if (lane < 2) {
        const u64 word = ((u64)(unsigned int)r << 32) | (u64)pack2bf(a, b);
        __hip_atomic_store(&H0T[(r & 1) * 512 + bid * 2 + lane], word,
                           __ATOMIC_RELAXED, __HIP_MEMORY_SCOPE_AGENT);
      }
    }
    if (w == 3 && r >= 2) {
      float hv = 0.f;
      if (lane < UB) {
        const int u = lane;
        float gi = bs1[u], gf = bs1[4 + u], gg = bs1[8 + u], go = bs1[12 + u];
#pragma unroll
        for (int p = 3; p < 7; ++p) {
          gi += gp[p * 16 + u];      gf += gp[p * 16 + 4 + u];
          gg += gp[p * 16 + 8 + u];  go += gp[p * 16 + 12 + u];
        }
        const float c = sigmoidf_(gf) * cst + sigmoidf_(gi) * tanhf_(gg);
        cst = c;
        hv = sigmoidf_(go) * tanhf_(c);
        if (r - 1 == T_SEQ) {
          float* h1f = reinterpret_cast<float*>(ws + WS_H1F);
          h1f[bid * UB + u] = hv;
          dout[VOCAB + HID + bid * UB + u] = hv;            // h_n layer1
          dout[VOCAB + 3 * HID + bid * UB + u] = cst;       // c_n layer1
        }
      }
      const float a = __shfl(hv, 2 * (lane & 1));
      const float b = __shfl(hv, 2 * (lane & 1) + 1);
      if (lane < 2) {
        const u64 word = ((u64)(unsigned int)(r - 1) << 32) | (u64)pack2bf(a, b);
        __hip_atomic_store(&H1T[((r - 1) & 1) * 512 + bid * 2 + lane], word,
                           __ATOMIC_RELAXED, __HIP_MEMORY_SCOPE_AGENT);
      }
    }
    // no trailing barrier: every consumer's next-round poll gates reuse,
    // and all LDS regions touched before sync(1) were last read pre-sync(2).
  }
}

// ---------------------------------------------------------------------------
__global__ __launch_bounds__(256) void logits_kernel(
    const float* __restrict__ wout, const float* __restrict__ bout,
    unsigned int* __restrict__ ws) {
  const float* h1f = reinterpret_cast<const float*>(ws + WS_H1F);
  float* lg = reinterpret_cast<float*>(ws + WS_LOG);
  const int lane = threadIdx.x & 63;
  const int wv = threadIdx.x >> 6;
  const int gw = blockIdx.x * 4 + wv;    // 1024 waves total
  const float4* h4 = reinterpret_cast<const float4*>(h1f);
  float4 h[4];
#pragma unroll
  for (int j = 0; j < 4; ++j) h[j] = h4[j * 64 + lane];
  for (int v = gw; v < VOCAB; v += 1024) {
    const float4* wr = reinterpret_cast<const float4*>(wout + (size_t)v * HID);
    float s = 0.f;
#pragma unroll
    for (int j = 0; j < 4; ++j) {
      float4 x = wr[j * 64 + lane];
      s += x.x * h[j].x + x.y * h[j].y + x.z * h[j].z + x.w * h[j].w;
    }
#pragma unroll
    for (int m = 32; m >= 1; m >>= 1) s += __shfl_xor(s, m, 64);
    if (lane == 0) lg[v] = s + bout[v];
  }
}

__global__ __launch_bounds__(1024) void lse_kernel(unsigned int* __restrict__ ws) {
  const float* lg = reinterpret_cast<const float*>(ws + WS_LOG);
  __shared__ float wred[16];
  __shared__ float mshare;
  const int tid = threadIdx.x;
  float m = -3.4e38f;
  for (int i = tid; i < VOCAB; i += 1024) m = fmaxf(m, lg[i]);
#pragma unroll
  for (int s = 32; s >= 1; s >>= 1) m = fmaxf(m, __shfl_xor(m, s, 64));
  if ((tid & 63) == 0) wred[tid >> 6] = m;
  __syncthreads();
  if (tid == 0) {
    float mm = wred[0];
    for (int i = 1; i < 16; ++i) mm = fmaxf(mm, wred[i]);
    mshare = mm;
  }
  __syncthreads();
  const float M = mshare;
  float a = 0.f;
  for (int i = tid; i < VOCAB; i += 1024) a += __expf(lg[i] - M);
#pragma unroll
  for (int s = 32; s >= 1; s >>= 1) a += __shfl_xor(a, s, 64);
  __syncthreads();
  if ((tid & 63) == 0) wred[tid >> 6] = a;
  __syncthreads();
  if (tid == 0) {
    float ss = 0.f;
    for (int i = 0; i < 16; ++i) ss += wred[i];
    reinterpret_cast<float*>(ws + WS_LSE)[0] = M + logf(ss);
  }
}

__global__ __launch_bounds__(256) void out_kernel(
    const unsigned int* __restrict__ ws, float* __restrict__ dout) {
  const float lse = reinterpret_cast<const float*>(ws + WS_LSE)[0];
  const float* lg = reinterpret_cast<const float*>(ws + WS_LOG);
  const int i = blockIdx.x * 256 + threadIdx.x;
  if (i < VOCAB) dout[i] = lg[i] - lse;
}

// ---------------------------------------------------------------------------
extern "C" void kernel_launch(void* const* d_in, const int* in_sizes, int n_in,
                              void* d_out, int out_size, void* d_ws, size_t ws_size,
                              hipStream_t stream) {
  const int*   tok  = (const int*)d_in[0];
  const float* h0in = (const float*)d_in[1];
  const float* c0in = (const float*)d_in[2];
  const float* emb  = (const float*)d_in[3];
  const float* wih0 = (const float*)d_in[4];
  const float* whh0 = (const float*)d_in[5];
  const float* bih0 = (const float*)d_in[6];
  const float* bhh0 = (const float*)d_in[7];
  const float* wih1 = (const float*)d_in[8];
  const float* whh1 = (const float*)d_in[9];
  const float* bih1 = (const float*)d_in[10];
  const float* bhh1 = (const float*)d_in[11];
  const float* wout = (const float*)d_in[12];
  const float* bout = (const float*)d_in[13];
  float* out = (float*)d_out;
  unsigned int* ws = (unsigned int*)d_ws;

  (void)in_sizes; (void)n_in; (void)out_size; (void)ws_size;

  (void)hipFuncSetAttribute((const void*)scan_kernel,
                            hipFuncAttributeMaxDynamicSharedMemorySize, SMEM_BYTES);

  reset_kernel<<<1, TPB, 0, stream>>>(h0in, ws);
  scan_kernel<<<NBLK, TPB, SMEM_BYTES, stream>>>(
      tok, h0in, c0in, emb, wih0, whh0, bih0, bhh0,
      wih1, whh1, bih1, bhh1, out, ws);
  logits_kernel<<<256, 256, 0, stream>>>(wout, bout, ws);
  lse_kernel<<<1, 1024, 0, stream>>>(ws);
  out_kernel<<<(VOCAB + 255) / 256, 256, 0, stream>>>(ws, out);
}